// Round 6
// baseline (586.742 us; speedup 1.0000x reference)
//
#include <hip/hip_runtime.h>

#define NN 100000
#define NE 600000
#define DIM 128
#define NG 256
#define NB_SCAN 391  // ceil(NN/256)

typedef __attribute__((ext_vector_type(8))) short short8_t;
typedef __attribute__((ext_vector_type(4))) float f32x4;

__device__ __forceinline__ ushort f2bf(float f) {
  unsigned u = __float_as_uint(f);
  unsigned r = (u + 0x7fffu + ((u >> 16) & 1u)) >> 16;
  return (ushort)r;
}
__device__ __forceinline__ float bf2f(ushort h) {
  return __uint_as_float(((unsigned)h) << 16);
}

// ---------------- embed + layernorm (wave per node) ----------------
__global__ __launch_bounds__(256) void embed_ln_kernel(
    const int* __restrict__ x_idx, const float* __restrict__ emb,
    const float* __restrict__ g, const float* __restrict__ b,
    float* __restrict__ out) {
  int wave = threadIdx.x >> 6;
  int lane = threadIdx.x & 63;
  int n = blockIdx.x * 4 + wave;
  if (n >= NN) return;
  int idx = x_idx[n];
  float2 v = ((const float2*)(emb + (size_t)idx * DIM))[lane];
  float s = v.x + v.y;
  float sq = v.x * v.x + v.y * v.y;
  for (int off = 32; off; off >>= 1) {
    s += __shfl_xor(s, off);
    sq += __shfl_xor(sq, off);
  }
  float m = s * (1.0f / 128.0f);
  float var = sq * (1.0f / 128.0f) - m * m;
  float r = rsqrtf(var + 1e-5f);
  float2 gg = ((const float2*)g)[lane];
  float2 bb = ((const float2*)b)[lane];
  float2 o;
  o.x = (v.x - m) * r * gg.x + bb.x;
  o.y = (v.y - m) * r * gg.y + bb.y;
  ((float2*)(out + (size_t)n * DIM))[lane] = o;
}

// ---------------- layernorm from buffer ----------------
__global__ __launch_bounds__(256) void ln_kernel(
    const float* __restrict__ in, const float* __restrict__ g,
    const float* __restrict__ b, float* __restrict__ out) {
  int wave = threadIdx.x >> 6;
  int lane = threadIdx.x & 63;
  int n = blockIdx.x * 4 + wave;
  if (n >= NN) return;
  float2 v = ((const float2*)(in + (size_t)n * DIM))[lane];
  float s = v.x + v.y;
  float sq = v.x * v.x + v.y * v.y;
  for (int off = 32; off; off >>= 1) {
    s += __shfl_xor(s, off);
    sq += __shfl_xor(sq, off);
  }
  float m = s * (1.0f / 128.0f);
  float var = sq * (1.0f / 128.0f) - m * m;
  float r = rsqrtf(var + 1e-5f);
  float2 gg = ((const float2*)g)[lane];
  float2 bb = ((const float2*)b)[lane];
  float2 o;
  o.x = (v.x - m) * r * gg.x + bb.x;
  o.y = (v.y - m) * r * gg.y + bb.y;
  ((float2*)(out + (size_t)n * DIM))[lane] = o;
}

// ---------------- CSR build ----------------
__global__ __launch_bounds__(256) void deg_int_kernel(const int* __restrict__ dst,
                                                      int* __restrict__ degi) {
  int e = blockIdx.x * 256 + threadIdx.x;
  if (e < NE) atomicAdd(degi + dst[e], 1);
}

__global__ __launch_bounds__(256) void scan1_kernel(const int* __restrict__ degi,
                                                    int* __restrict__ excl,
                                                    int* __restrict__ bsum) {
  __shared__ int tmp[256];
  int t = threadIdx.x;
  int i = blockIdx.x * 256 + t;
  int v = (i < NN) ? degi[i] : 0;
  int val = v;
  tmp[t] = val;
  __syncthreads();
  for (int off = 1; off < 256; off <<= 1) {
    int add = (t >= off) ? tmp[t - off] : 0;
    __syncthreads();
    val += add;
    tmp[t] = val;
    __syncthreads();
  }
  if (i < NN) excl[i] = val - v;
  if (t == 255) bsum[blockIdx.x] = val;
}

__global__ __launch_bounds__(512) void scan2_kernel(int* __restrict__ bsum,
                                                    int* __restrict__ bscan) {
  __shared__ int tmp[512];
  int t = threadIdx.x;
  int v = (t < NB_SCAN) ? bsum[t] : 0;
  int val = v;
  tmp[t] = val;
  __syncthreads();
  for (int off = 1; off < 512; off <<= 1) {
    int add = (t >= off) ? tmp[t - off] : 0;
    __syncthreads();
    val += add;
    tmp[t] = val;
    __syncthreads();
  }
  if (t < NB_SCAN) bscan[t] = val - v;
}

__global__ __launch_bounds__(256) void scan3_kernel(const int* __restrict__ excl,
                                                    const int* __restrict__ bscan,
                                                    int* __restrict__ row_off,
                                                    int* __restrict__ cursor) {
  int i = blockIdx.x * 256 + threadIdx.x;
  if (i < NN) {
    int r = excl[i] + bscan[i >> 8];
    row_off[i] = r;
    cursor[i] = r;
  }
  if (i == 0) row_off[NN] = NE;
}

__global__ __launch_bounds__(256) void fill_kernel(const int* __restrict__ src,
                                                   const int* __restrict__ dst,
                                                   int* __restrict__ cursor,
                                                   int* __restrict__ csr_src) {
  int e = blockIdx.x * 256 + threadIdx.x;
  if (e < NE) {
    int d = dst[e];
    int slot = atomicAdd(cursor + d, 1);
    csr_src[slot] = src[e];
  }
}

// ---------------- gather mean ----------------
__global__ __launch_bounds__(256) void gather_mean_kernel(
    const int* __restrict__ row_off, const int* __restrict__ csr_src,
    const float* __restrict__ x, float* __restrict__ agg) {
  int t = threadIdx.x;
  int q = t & 31;
  int node = blockIdx.x * 8 + (t >> 5);
  if (node >= NN) return;
  int beg = row_off[node], end = row_off[node + 1];
  float4 acc = make_float4(0.f, 0.f, 0.f, 0.f);
  for (int e = beg; e < end; ++e) {
    int s = csr_src[e];
    float4 v = ((const float4*)(x + (size_t)s * DIM))[q];
    acc.x += v.x; acc.y += v.y; acc.z += v.z; acc.w += v.w;
  }
  float sc = 1.0f / fmaxf((float)(end - beg), 1.0f);
  acc.x *= sc; acc.y *= sc; acc.z *= sc; acc.w *= sc;
  ((float4*)(agg + (size_t)node * DIM))[q] = acc;
}

// ---------------- weight split+permute: Wcat[h][k] k<128->wl, else wr ----------------
// k permuted within each 32-block so a lane's 8 MFMA operand elems are contiguous:
// lane needs k = {q*4+0..3, 16+q*4+0..3}, q=lane>>4.
__global__ __launch_bounds__(256) void prep_w_kernel(const float* __restrict__ wl,
                                                     const float* __restrict__ wr,
                                                     ushort* __restrict__ whi,
                                                     ushort* __restrict__ wlo) {
  int t = blockIdx.x * 256 + threadIdx.x;  // 32768
  int h = t >> 8, k = t & 255;
  float v = (k < 128) ? wl[h * 128 + k] : wr[h * 128 + (k - 128)];
  int r = k & 31;
  int pos = (r < 16) ? ((r >> 2) * 8 + (r & 3)) : (((r & 15) >> 2) * 8 + 4 + (r & 3));
  int oc = (k & ~31) + pos;
  ushort hi = f2bf(v);
  whi[h * 256 + oc] = hi;
  wlo[h * 256 + oc] = f2bf(v - bf2f(hi));
}

// ---------------- SAGE conv via split-bf16 MFMA ----------------
// out = relu([agg|x] @ Wcat^T + bl), K=256, 3-term split product.
// Block: 128 nodes x 128 h; 4 waves each 32 nodes x 128 h.
__global__ __launch_bounds__(256, 2) void conv_mfma_kernel(
    const float* __restrict__ xln, const float* __restrict__ agg,
    const ushort* __restrict__ whi, const ushort* __restrict__ wlo,
    const float* __restrict__ bl, float* __restrict__ out) {
  __shared__ ushort Xs[2][128 * 64];  // [hi/lo][row*64 + permuted k] = 32 KB
  const int t = threadIdx.x;
  const int lane = t & 63;
  const int wv = t >> 6;
  const int l15 = lane & 15;
  const int lq = lane >> 4;
  const int nbase = blockIdx.x * 128;

  f32x4 acc[2][8];
#pragma unroll
  for (int a = 0; a < 2; ++a)
#pragma unroll
    for (int b = 0; b < 8; ++b) acc[a][b] = (f32x4){0.f, 0.f, 0.f, 0.f};

  const int srow = t >> 1;   // staging row 0..127
  const int sh2 = t & 1;     // staging half
  const int gn_s = nbase + srow;
  const bool sval = gn_s < NN;
  char* lds_hi = (char*)&Xs[0][0];
  char* lds_lo = (char*)&Xs[1][0];
  const int sswz = (srow & 7) << 4;

  for (int p = 0; p < 4; ++p) {
    const float* srcp = (p < 2) ? agg : xln;
    const int kb = (p & 1) * 64;
    // ---- stage: 128 rows x 64 k fp32 -> bf16 hi/lo, k-permuted, swizzled
#pragma unroll
    for (int i = 0; i < 8; ++i) {
      int qd = sh2 * 8 + i;  // float4-quad within phase (k = qd*4)
      float4 v = make_float4(0.f, 0.f, 0.f, 0.f);
      if (sval) v = *(const float4*)(srcp + (size_t)gn_s * DIM + kb + qd * 4);
      int j = qd >> 3;   // 32-k block
      int a = qd & 7;    // quad within block
      int inner = j * 64 + ((a < 4) ? a * 16 : (a - 4) * 16 + 8);
      int off = srow * 128 + inner;
      ushort4 hi, lo;
      hi.x = f2bf(v.x); lo.x = f2bf(v.x - bf2f(hi.x));
      hi.y = f2bf(v.y); lo.y = f2bf(v.y - bf2f(hi.y));
      hi.z = f2bf(v.z); lo.z = f2bf(v.z - bf2f(hi.z));
      hi.w = f2bf(v.w); lo.w = f2bf(v.w - bf2f(hi.w));
      *(ushort4*)(lds_hi + (off ^ sswz)) = hi;
      *(ushort4*)(lds_lo + (off ^ sswz)) = lo;
    }
    __syncthreads();
    // ---- compute: 2 k-steps of 32
#pragma unroll
    for (int j = 0; j < 2; ++j) {
      short8_t ahi[2], alo[2];
#pragma unroll
      for (int nt = 0; nt < 2; ++nt) {
        int row = wv * 32 + nt * 16 + l15;
        int off = row * 128 + j * 64 + lq * 16;
        int sw = (row & 7) << 4;
        ahi[nt] = *(short8_t*)(lds_hi + (off ^ sw));
        alo[nt] = *(short8_t*)(lds_lo + (off ^ sw));
      }
#pragma unroll
      for (int ht = 0; ht < 8; ++ht) {
        int woff = (ht * 16 + l15) * 256 + p * 64 + j * 32 + lq * 8;
        short8_t bhi = *(const short8_t*)(whi + woff);
        short8_t blo = *(const short8_t*)(wlo + woff);
        acc[0][ht] = __builtin_amdgcn_mfma_f32_16x16x32_bf16(ahi[0], bhi, acc[0][ht], 0, 0, 0);
        acc[1][ht] = __builtin_amdgcn_mfma_f32_16x16x32_bf16(ahi[1], bhi, acc[1][ht], 0, 0, 0);
        acc[0][ht] = __builtin_amdgcn_mfma_f32_16x16x32_bf16(alo[0], bhi, acc[0][ht], 0, 0, 0);
        acc[1][ht] = __builtin_amdgcn_mfma_f32_16x16x32_bf16(alo[1], bhi, acc[1][ht], 0, 0, 0);
        acc[0][ht] = __builtin_amdgcn_mfma_f32_16x16x32_bf16(ahi[0], blo, acc[0][ht], 0, 0, 0);
        acc[1][ht] = __builtin_amdgcn_mfma_f32_16x16x32_bf16(ahi[1], blo, acc[1][ht], 0, 0, 0);
      }
    }
    __syncthreads();
  }
  // ---- epilogue: bias + relu, C layout col=lane&15, row=(lane>>4)*4+reg
#pragma unroll
  for (int ht = 0; ht < 8; ++ht) {
    float bv = bl[ht * 16 + l15];
#pragma unroll
    for (int nt = 0; nt < 2; ++nt) {
#pragma unroll
      for (int r = 0; r < 4; ++r) {
        int node = nbase + wv * 32 + nt * 16 + lq * 4 + r;
        if (node < NN)
          out[(size_t)node * DIM + ht * 16 + l15] = fmaxf(acc[nt][ht][r] + bv, 0.f);
      }
    }
  }
}

// ---------------- mean pool over sorted batch ----------------
#define PCHUNK 128
__global__ __launch_bounds__(128) void pool_kernel(const float* __restrict__ x,
                                                   const int* __restrict__ batch,
                                                   float* __restrict__ pool,
                                                   float* __restrict__ cnt) {
  int f = threadIdx.x;
  int n0 = blockIdx.x * PCHUNK;
  float acc = 0.f;
  int cur = batch[n0];
  int runlen = 0;
  for (int i = 0; i < PCHUNK; ++i) {
    int n = n0 + i;
    if (n >= NN) break;
    int bg = batch[n];
    if (bg != cur) {
      atomicAdd(&pool[cur * DIM + f], acc);
      if (f == 0) atomicAdd(&cnt[cur], (float)runlen);
      acc = 0.f;
      runlen = 0;
      cur = bg;
    }
    acc += x[(size_t)n * DIM + f];
    runlen++;
  }
  if (runlen > 0) {
    atomicAdd(&pool[cur * DIM + f], acc);
    if (f == 0) atomicAdd(&cnt[cur], (float)runlen);
  }
}

// ---------------- MLP head ----------------
__global__ __launch_bounds__(128) void head_kernel(
    const float* __restrict__ pool, const float* __restrict__ cnt,
    const float* __restrict__ w1, const float* __restrict__ b1,
    const float* __restrict__ w2, const float* __restrict__ b2,
    float* __restrict__ out) {
  __shared__ float gsh[128];
  __shared__ float h[64];
  int g = blockIdx.x;
  int t = threadIdx.x;
  float ic = 1.0f / fmaxf(cnt[g], 1.0f);
  gsh[t] = pool[g * DIM + t] * ic;
  __syncthreads();
  if (t < 64) {
    float a = b1[t];
#pragma unroll 8
    for (int k = 0; k < 128; ++k) a += gsh[k] * w1[t * 128 + k];
    h[t] = fmaxf(a, 0.f);
  }
  __syncthreads();
  if (t < 2) {
    float a = b2[t];
#pragma unroll
    for (int k = 0; k < 64; ++k) a += h[k] * w2[t * 64 + k];
    out[g * 2 + t] = a;
  }
}

extern "C" void kernel_launch(void* const* d_in, const int* in_sizes, int n_in,
                              void* d_out, int out_size, void* d_ws, size_t ws_size,
                              hipStream_t stream) {
  const int* x_idx = (const int*)d_in[0];
  const int* eidx = (const int*)d_in[1];
  const int* batch = (const int*)d_in[2];
  const float* emb = (const float*)d_in[3];
  const float* ln0g = (const float*)d_in[4];
  const float* ln0b = (const float*)d_in[5];
  const float* w0l = (const float*)d_in[6];
  const float* b0l = (const float*)d_in[7];
  const float* w0r = (const float*)d_in[8];
  const float* ln1g = (const float*)d_in[9];
  const float* ln1b = (const float*)d_in[10];
  const float* w1l = (const float*)d_in[11];
  const float* b1l = (const float*)d_in[12];
  const float* w1r = (const float*)d_in[13];
  const float* mw1 = (const float*)d_in[14];
  const float* mb1 = (const float*)d_in[15];
  const float* mw2 = (const float*)d_in[16];
  const float* mb2 = (const float*)d_in[17];
  float* out = (float*)d_out;

  float* ws = (float*)d_ws;
  float* x = ws;                                  // NN*DIM
  float* agg = x + (size_t)NN * DIM;              // NN*DIM
  float* pool = agg + (size_t)NN * DIM;           // NG*DIM
  float* cnt = pool + (size_t)NG * DIM;           // NG
  ushort* w0hi = (ushort*)(cnt + NG);             // 32768 ushort each
  ushort* w0lo = w0hi + 32768;
  ushort* w1hi = w0lo + 32768;
  ushort* w1lo = w1hi + 32768;
  int* degi = (int*)(w1lo + 32768);               // NN
  int* excl = degi + NN;                          // NN
  int* row_off = excl + NN;                       // NN+1
  int* cursor = row_off + NN + 1;                 // NN
  int* bsum = cursor + NN;                        // 512
  int* bscan = bsum + 512;                        // 512
  int* csr_src = bscan + 512;                     // NE

  const int* src = eidx;
  const int* dst = eidx + NE;

  hipMemsetAsync(pool, 0, ((size_t)NG * DIM + NG) * sizeof(float), stream);
  hipMemsetAsync(degi, 0, (size_t)NN * sizeof(int), stream);

  // CSR build (once, reused by both layers)
  deg_int_kernel<<<(NE + 255) / 256, 256, 0, stream>>>(dst, degi);
  scan1_kernel<<<NB_SCAN, 256, 0, stream>>>(degi, excl, bsum);
  scan2_kernel<<<1, 512, 0, stream>>>(bsum, bscan);
  scan3_kernel<<<NB_SCAN, 256, 0, stream>>>(excl, bscan, row_off, cursor);
  fill_kernel<<<(NE + 255) / 256, 256, 0, stream>>>(src, dst, cursor, csr_src);

  // weight split+permute (replaces fp32 transposes)
  prep_w_kernel<<<128, 256, 0, stream>>>(w0l, w0r, w0hi, w0lo);
  prep_w_kernel<<<128, 256, 0, stream>>>(w1l, w1r, w1hi, w1lo);

  embed_ln_kernel<<<NN / 4, 256, 0, stream>>>(x_idx, emb, ln0g, ln0b, x);

  // layer 0
  gather_mean_kernel<<<(NN + 7) / 8, 256, 0, stream>>>(row_off, csr_src, x, agg);
  conv_mfma_kernel<<<(NN + 127) / 128, 256, 0, stream>>>(x, agg, w0hi, w0lo, b0l, agg);
  // layer 1
  ln_kernel<<<NN / 4, 256, 0, stream>>>(agg, ln1g, ln1b, x);
  gather_mean_kernel<<<(NN + 7) / 8, 256, 0, stream>>>(row_off, csr_src, x, agg);
  conv_mfma_kernel<<<(NN + 127) / 128, 256, 0, stream>>>(x, agg, w1hi, w1lo, b1l, agg);

  pool_kernel<<<(NN + PCHUNK - 1) / PCHUNK, 128, 0, stream>>>(agg, batch, pool, cnt);
  head_kernel<<<NG, 128, 0, stream>>>(pool, cnt, mw1, mb1, mw2, mb2, out);
}

// Round 7
// 475.046 us; speedup vs baseline: 1.2351x; 1.2351x over previous
//
#include <hip/hip_runtime.h>

#define NN 100000
#define NE 600000
#define DIM 128
#define NG 256
#define NB_SCAN 391  // ceil(NN/256)

typedef __attribute__((ext_vector_type(8))) short short8_t;
typedef __attribute__((ext_vector_type(4))) float f32x4;

__device__ __forceinline__ ushort f2bf(float f) {
  unsigned u = __float_as_uint(f);
  unsigned r = (u + 0x7fffu + ((u >> 16) & 1u)) >> 16;
  return (ushort)r;
}
__device__ __forceinline__ float bf2f(ushort h) {
  return __uint_as_float(((unsigned)h) << 16);
}

// ---------------- embed + layernorm (wave per node) ----------------
__global__ __launch_bounds__(256) void embed_ln_kernel(
    const int* __restrict__ x_idx, const float* __restrict__ emb,
    const float* __restrict__ g, const float* __restrict__ b,
    float* __restrict__ out) {
  int wave = threadIdx.x >> 6;
  int lane = threadIdx.x & 63;
  int n = blockIdx.x * 4 + wave;
  if (n >= NN) return;
  int idx = x_idx[n];
  float2 v = ((const float2*)(emb + (size_t)idx * DIM))[lane];
  float s = v.x + v.y;
  float sq = v.x * v.x + v.y * v.y;
  for (int off = 32; off; off >>= 1) {
    s += __shfl_xor(s, off);
    sq += __shfl_xor(sq, off);
  }
  float m = s * (1.0f / 128.0f);
  float var = sq * (1.0f / 128.0f) - m * m;
  float r = rsqrtf(var + 1e-5f);
  float2 gg = ((const float2*)g)[lane];
  float2 bb = ((const float2*)b)[lane];
  float2 o;
  o.x = (v.x - m) * r * gg.x + bb.x;
  o.y = (v.y - m) * r * gg.y + bb.y;
  ((float2*)(out + (size_t)n * DIM))[lane] = o;
}

// ---------------- layernorm from buffer ----------------
__global__ __launch_bounds__(256) void ln_kernel(
    const float* __restrict__ in, const float* __restrict__ g,
    const float* __restrict__ b, float* __restrict__ out) {
  int wave = threadIdx.x >> 6;
  int lane = threadIdx.x & 63;
  int n = blockIdx.x * 4 + wave;
  if (n >= NN) return;
  float2 v = ((const float2*)(in + (size_t)n * DIM))[lane];
  float s = v.x + v.y;
  float sq = v.x * v.x + v.y * v.y;
  for (int off = 32; off; off >>= 1) {
    s += __shfl_xor(s, off);
    sq += __shfl_xor(sq, off);
  }
  float m = s * (1.0f / 128.0f);
  float var = sq * (1.0f / 128.0f) - m * m;
  float r = rsqrtf(var + 1e-5f);
  float2 gg = ((const float2*)g)[lane];
  float2 bb = ((const float2*)b)[lane];
  float2 o;
  o.x = (v.x - m) * r * gg.x + bb.x;
  o.y = (v.y - m) * r * gg.y + bb.y;
  ((float2*)(out + (size_t)n * DIM))[lane] = o;
}

// ---------------- CSR build ----------------
__global__ __launch_bounds__(256) void deg_int_kernel(const int* __restrict__ dst,
                                                      int* __restrict__ degi) {
  int e = blockIdx.x * 256 + threadIdx.x;
  if (e < NE) atomicAdd(degi + dst[e], 1);
}

__global__ __launch_bounds__(256) void scan1_kernel(const int* __restrict__ degi,
                                                    int* __restrict__ excl,
                                                    int* __restrict__ bsum) {
  __shared__ int tmp[256];
  int t = threadIdx.x;
  int i = blockIdx.x * 256 + t;
  int v = (i < NN) ? degi[i] : 0;
  int val = v;
  tmp[t] = val;
  __syncthreads();
  for (int off = 1; off < 256; off <<= 1) {
    int add = (t >= off) ? tmp[t - off] : 0;
    __syncthreads();
    val += add;
    tmp[t] = val;
    __syncthreads();
  }
  if (i < NN) excl[i] = val - v;
  if (t == 255) bsum[blockIdx.x] = val;
}

__global__ __launch_bounds__(512) void scan2_kernel(int* __restrict__ bsum,
                                                    int* __restrict__ bscan) {
  __shared__ int tmp[512];
  int t = threadIdx.x;
  int v = (t < NB_SCAN) ? bsum[t] : 0;
  int val = v;
  tmp[t] = val;
  __syncthreads();
  for (int off = 1; off < 512; off <<= 1) {
    int add = (t >= off) ? tmp[t - off] : 0;
    __syncthreads();
    val += add;
    tmp[t] = val;
    __syncthreads();
  }
  if (t < NB_SCAN) bscan[t] = val - v;
}

__global__ __launch_bounds__(256) void scan3_kernel(const int* __restrict__ excl,
                                                    const int* __restrict__ bscan,
                                                    int* __restrict__ row_off,
                                                    int* __restrict__ cursor) {
  int i = blockIdx.x * 256 + threadIdx.x;
  if (i < NN) {
    int r = excl[i] + bscan[i >> 8];
    row_off[i] = r;
    cursor[i] = r;
  }
  if (i == 0) row_off[NN] = NE;
}

__global__ __launch_bounds__(256) void fill_kernel(const int* __restrict__ src,
                                                   const int* __restrict__ dst,
                                                   int* __restrict__ cursor,
                                                   int* __restrict__ csr_src) {
  int e = blockIdx.x * 256 + threadIdx.x;
  if (e < NE) {
    int d = dst[e];
    int slot = atomicAdd(cursor + d, 1);
    csr_src[slot] = src[e];
  }
}

// ---------------- gather mean ----------------
__global__ __launch_bounds__(256) void gather_mean_kernel(
    const int* __restrict__ row_off, const int* __restrict__ csr_src,
    const float* __restrict__ x, float* __restrict__ agg) {
  int t = threadIdx.x;
  int q = t & 31;
  int node = blockIdx.x * 8 + (t >> 5);
  if (node >= NN) return;
  int beg = row_off[node], end = row_off[node + 1];
  float4 acc = make_float4(0.f, 0.f, 0.f, 0.f);
  for (int e = beg; e < end; ++e) {
    int s = csr_src[e];
    float4 v = ((const float4*)(x + (size_t)s * DIM))[q];
    acc.x += v.x; acc.y += v.y; acc.z += v.z; acc.w += v.w;
  }
  float sc = 1.0f / fmaxf((float)(end - beg), 1.0f);
  acc.x *= sc; acc.y *= sc; acc.z *= sc; acc.w *= sc;
  ((float4*)(agg + (size_t)node * DIM))[q] = acc;
}

// ---------------- weight split into per-lane fragment order ----------------
// wp layout: [p][hl][j][ht][lane][8] ushort; p=phase(0..3), hl=hi/lo, j=k32-block,
// ht=h-tile(0..7), lane=0..63. Lane (lq=lane>>4,l15=lane&15) elem e maps to
// h = ht*16+l15, k = p*64 + j*32 + lq*4 + (e&3) + 16*(e>>2). Coalesced 16B/lane.
__global__ __launch_bounds__(256) void prep_w_kernel(const float* __restrict__ wl,
                                                     const float* __restrict__ wr,
                                                     ushort* __restrict__ wp) {
  int t = blockIdx.x * 256 + threadIdx.x;  // 32768 = p*j*ht*lane*e
  int e = t & 7;
  int lane = (t >> 3) & 63;
  int ht = (t >> 9) & 7;
  int j = (t >> 12) & 1;
  int p = (t >> 13) & 3;
  int h = ht * 16 + (lane & 15);
  int lq = lane >> 4;
  int k = p * 64 + j * 32 + lq * 4 + (e & 3) + 16 * (e >> 2);
  float v = (k < 128) ? wl[h * 128 + k] : wr[h * 128 + (k - 128)];
  ushort hi = f2bf(v);
  ushort lo = f2bf(v - bf2f(hi));
  wp[(((p * 2 + 0) * 2 + j) * 8 + ht) * 512 + lane * 8 + e] = hi;
  wp[(((p * 2 + 1) * 2 + j) * 8 + ht) * 512 + lane * 8 + e] = lo;
}

// ---------------- SAGE conv via split-bf16 MFMA, W staged in LDS ----------------
// out = relu([agg|x] @ Wcat^T + bl), K=256, 3-term split product.
// Block: 128 nodes x 128 h; 4 waves each 32 nodes x 128 h.
__global__ __launch_bounds__(256, 2) void conv_mfma_kernel(
    const float* __restrict__ xln, const float* __restrict__ agg,
    const ushort* __restrict__ wp, const float* __restrict__ bl,
    float* __restrict__ out) {
  __shared__ ushort Xs[2][128 * 64];  // 32 KB: [hi/lo][row*64 + permuted k]
  __shared__ ushort Wl[16384];        // 32 KB: per-phase W slice [hl][j][ht][lane][8]
  const int t = threadIdx.x;
  const int lane = t & 63;
  const int wv = t >> 6;
  const int l15 = lane & 15;
  const int lq = lane >> 4;
  const int nbase = blockIdx.x * 128;

  f32x4 acc[2][8];
#pragma unroll
  for (int a = 0; a < 2; ++a)
#pragma unroll
    for (int b = 0; b < 8; ++b) acc[a][b] = (f32x4){0.f, 0.f, 0.f, 0.f};

  const int srow = t >> 1;   // staging row 0..127
  const int sh2 = t & 1;     // staging half
  const int gn_s = nbase + srow;
  const bool sval = gn_s < NN;
  char* lds_hi = (char*)&Xs[0][0];
  char* lds_lo = (char*)&Xs[1][0];
  const int sswz = (srow & 7) << 4;

  for (int p = 0; p < 4; ++p) {
    const float* srcp = (p < 2) ? agg : xln;
    const int kb = (p & 1) * 64;
    // ---- stage W slice for this phase: 32 KB, fully coalesced
    {
      const ushort* wsrc = wp + p * 16384;
#pragma unroll
      for (int i = 0; i < 8; ++i)
        *(short8_t*)(Wl + i * 2048 + t * 8) = *(const short8_t*)(wsrc + i * 2048 + t * 8);
    }
    // ---- stage X: 128 rows x 64 k fp32 -> bf16 hi/lo, k-permuted, swizzled
#pragma unroll
    for (int i = 0; i < 8; ++i) {
      int qd = sh2 * 8 + i;  // float4-quad within phase (k = qd*4)
      float4 v = make_float4(0.f, 0.f, 0.f, 0.f);
      if (sval) v = *(const float4*)(srcp + (size_t)gn_s * DIM + kb + qd * 4);
      int j = qd >> 3;   // 32-k block
      int a = qd & 7;    // quad within block
      int inner = j * 64 + ((a < 4) ? a * 16 : (a - 4) * 16 + 8);
      int off = srow * 128 + inner;
      ushort4 hi, lo;
      hi.x = f2bf(v.x); lo.x = f2bf(v.x - bf2f(hi.x));
      hi.y = f2bf(v.y); lo.y = f2bf(v.y - bf2f(hi.y));
      hi.z = f2bf(v.z); lo.z = f2bf(v.z - bf2f(hi.z));
      hi.w = f2bf(v.w); lo.w = f2bf(v.w - bf2f(hi.w));
      *(ushort4*)(lds_hi + (off ^ sswz)) = hi;
      *(ushort4*)(lds_lo + (off ^ sswz)) = lo;
    }
    __syncthreads();
    // ---- compute: 2 k-steps of 32
#pragma unroll
    for (int j = 0; j < 2; ++j) {
      short8_t ahi[2], alo[2];
#pragma unroll
      for (int nt = 0; nt < 2; ++nt) {
        int row = wv * 32 + nt * 16 + l15;
        int off = row * 128 + j * 64 + lq * 16;
        int sw = (row & 7) << 4;
        ahi[nt] = *(short8_t*)(lds_hi + (off ^ sw));
        alo[nt] = *(short8_t*)(lds_lo + (off ^ sw));
      }
#pragma unroll
      for (int ht = 0; ht < 8; ++ht) {
        short8_t bhi = *(const short8_t*)(Wl + ((0 * 2 + j) * 8 + ht) * 512 + lane * 8);
        short8_t blo = *(const short8_t*)(Wl + ((1 * 2 + j) * 8 + ht) * 512 + lane * 8);
        acc[0][ht] = __builtin_amdgcn_mfma_f32_16x16x32_bf16(ahi[0], bhi, acc[0][ht], 0, 0, 0);
        acc[1][ht] = __builtin_amdgcn_mfma_f32_16x16x32_bf16(ahi[1], bhi, acc[1][ht], 0, 0, 0);
        acc[0][ht] = __builtin_amdgcn_mfma_f32_16x16x32_bf16(alo[0], bhi, acc[0][ht], 0, 0, 0);
        acc[1][ht] = __builtin_amdgcn_mfma_f32_16x16x32_bf16(alo[1], bhi, acc[1][ht], 0, 0, 0);
        acc[0][ht] = __builtin_amdgcn_mfma_f32_16x16x32_bf16(ahi[0], blo, acc[0][ht], 0, 0, 0);
        acc[1][ht] = __builtin_amdgcn_mfma_f32_16x16x32_bf16(ahi[1], blo, acc[1][ht], 0, 0, 0);
      }
    }
    __syncthreads();
  }
  // ---- epilogue: bias + relu, C layout col=lane&15, row=(lane>>4)*4+reg
#pragma unroll
  for (int ht = 0; ht < 8; ++ht) {
    float bv = bl[ht * 16 + l15];
#pragma unroll
    for (int nt = 0; nt < 2; ++nt) {
#pragma unroll
      for (int r = 0; r < 4; ++r) {
        int node = nbase + wv * 32 + nt * 16 + lq * 4 + r;
        if (node < NN)
          out[(size_t)node * DIM + ht * 16 + l15] = fmaxf(acc[nt][ht][r] + bv, 0.f);
      }
    }
  }
}

// ---------------- mean pool over sorted batch ----------------
#define PCHUNK 128
__global__ __launch_bounds__(128) void pool_kernel(const float* __restrict__ x,
                                                   const int* __restrict__ batch,
                                                   float* __restrict__ pool,
                                                   float* __restrict__ cnt) {
  int f = threadIdx.x;
  int n0 = blockIdx.x * PCHUNK;
  float acc = 0.f;
  int cur = batch[n0];
  int runlen = 0;
  for (int i = 0; i < PCHUNK; ++i) {
    int n = n0 + i;
    if (n >= NN) break;
    int bg = batch[n];
    if (bg != cur) {
      atomicAdd(&pool[cur * DIM + f], acc);
      if (f == 0) atomicAdd(&cnt[cur], (float)runlen);
      acc = 0.f;
      runlen = 0;
      cur = bg;
    }
    acc += x[(size_t)n * DIM + f];
    runlen++;
  }
  if (runlen > 0) {
    atomicAdd(&pool[cur * DIM + f], acc);
    if (f == 0) atomicAdd(&cnt[cur], (float)runlen);
  }
}

// ---------------- MLP head ----------------
__global__ __launch_bounds__(128) void head_kernel(
    const float* __restrict__ pool, const float* __restrict__ cnt,
    const float* __restrict__ w1, const float* __restrict__ b1,
    const float* __restrict__ w2, const float* __restrict__ b2,
    float* __restrict__ out) {
  __shared__ float gsh[128];
  __shared__ float h[64];
  int g = blockIdx.x;
  int t = threadIdx.x;
  float ic = 1.0f / fmaxf(cnt[g], 1.0f);
  gsh[t] = pool[g * DIM + t] * ic;
  __syncthreads();
  if (t < 64) {
    float a = b1[t];
#pragma unroll 8
    for (int k = 0; k < 128; ++k) a += gsh[k] * w1[t * 128 + k];
    h[t] = fmaxf(a, 0.f);
  }
  __syncthreads();
  if (t < 2) {
    float a = b2[t];
#pragma unroll
    for (int k = 0; k < 64; ++k) a += h[k] * w2[t * 64 + k];
    out[g * 2 + t] = a;
  }
}

extern "C" void kernel_launch(void* const* d_in, const int* in_sizes, int n_in,
                              void* d_out, int out_size, void* d_ws, size_t ws_size,
                              hipStream_t stream) {
  const int* x_idx = (const int*)d_in[0];
  const int* eidx = (const int*)d_in[1];
  const int* batch = (const int*)d_in[2];
  const float* emb = (const float*)d_in[3];
  const float* ln0g = (const float*)d_in[4];
  const float* ln0b = (const float*)d_in[5];
  const float* w0l = (const float*)d_in[6];
  const float* b0l = (const float*)d_in[7];
  const float* w0r = (const float*)d_in[8];
  const float* ln1g = (const float*)d_in[9];
  const float* ln1b = (const float*)d_in[10];
  const float* w1l = (const float*)d_in[11];
  const float* b1l = (const float*)d_in[12];
  const float* w1r = (const float*)d_in[13];
  const float* mw1 = (const float*)d_in[14];
  const float* mb1 = (const float*)d_in[15];
  const float* mw2 = (const float*)d_in[16];
  const float* mb2 = (const float*)d_in[17];
  float* out = (float*)d_out;

  float* ws = (float*)d_ws;
  float* x = ws;                                  // NN*DIM
  float* agg = x + (size_t)NN * DIM;              // NN*DIM
  float* pool = agg + (size_t)NN * DIM;           // NG*DIM
  float* cnt = pool + (size_t)NG * DIM;           // NG
  ushort* wp0 = (ushort*)(cnt + NG);              // 65536 ushort each
  ushort* wp1 = wp0 + 65536;
  int* degi = (int*)(wp1 + 65536);                // NN
  int* excl = degi + NN;                          // NN
  int* row_off = excl + NN;                       // NN+1
  int* cursor = row_off + NN + 1;                 // NN
  int* bsum = cursor + NN;                        // 512
  int* bscan = bsum + 512;                        // 512
  int* csr_src = bscan + 512;                     // NE

  const int* src = eidx;
  const int* dst = eidx + NE;

  hipMemsetAsync(pool, 0, ((size_t)NG * DIM + NG) * sizeof(float), stream);
  hipMemsetAsync(degi, 0, (size_t)NN * sizeof(int), stream);

  // CSR build (once, reused by both layers)
  deg_int_kernel<<<(NE + 255) / 256, 256, 0, stream>>>(dst, degi);
  scan1_kernel<<<NB_SCAN, 256, 0, stream>>>(degi, excl, bsum);
  scan2_kernel<<<1, 512, 0, stream>>>(bsum, bscan);
  scan3_kernel<<<NB_SCAN, 256, 0, stream>>>(excl, bscan, row_off, cursor);
  fill_kernel<<<(NE + 255) / 256, 256, 0, stream>>>(src, dst, cursor, csr_src);

  // weight split into per-lane fragment order
  prep_w_kernel<<<128, 256, 0, stream>>>(w0l, w0r, wp0);
  prep_w_kernel<<<128, 256, 0, stream>>>(w1l, w1r, wp1);

  embed_ln_kernel<<<NN / 4, 256, 0, stream>>>(x_idx, emb, ln0g, ln0b, x);

  // layer 0
  gather_mean_kernel<<<(NN + 7) / 8, 256, 0, stream>>>(row_off, csr_src, x, agg);
  conv_mfma_kernel<<<(NN + 127) / 128, 256, 0, stream>>>(x, agg, wp0, b0l, agg);
  // layer 1
  ln_kernel<<<NN / 4, 256, 0, stream>>>(agg, ln1g, ln1b, x);
  gather_mean_kernel<<<(NN + 7) / 8, 256, 0, stream>>>(row_off, csr_src, x, agg);
  conv_mfma_kernel<<<(NN + 127) / 128, 256, 0, stream>>>(x, agg, wp1, b1l, agg);

  pool_kernel<<<(NN + PCHUNK - 1) / PCHUNK, 128, 0, stream>>>(agg, batch, pool, cnt);
  head_kernel<<<NG, 128, 0, stream>>>(pool, cnt, mw1, mb1, mw2, mb2, out);
}

// Round 8
// 461.653 us; speedup vs baseline: 1.2710x; 1.0290x over previous
//
#include <hip/hip_runtime.h>

#define NN 100000
#define NE 600000
#define DIM 128
#define NG 256
#define NB_SCAN 391  // ceil(NN/256)

typedef __attribute__((ext_vector_type(8))) short short8_t;
typedef __attribute__((ext_vector_type(4))) float f32x4;

__device__ __forceinline__ ushort f2bf(float f) {
  unsigned u = __float_as_uint(f);
  unsigned r = (u + 0x7fffu + ((u >> 16) & 1u)) >> 16;
  return (ushort)r;
}
__device__ __forceinline__ float bf2f(ushort h) {
  return __uint_as_float(((unsigned)h) << 16);
}

// ---------------- embed + layernorm (wave per node) ----------------
__global__ __launch_bounds__(256) void embed_ln_kernel(
    const int* __restrict__ x_idx, const float* __restrict__ emb,
    const float* __restrict__ g, const float* __restrict__ b,
    float* __restrict__ out) {
  int wave = threadIdx.x >> 6;
  int lane = threadIdx.x & 63;
  int n = blockIdx.x * 4 + wave;
  if (n >= NN) return;
  int idx = x_idx[n];
  float2 v = ((const float2*)(emb + (size_t)idx * DIM))[lane];
  float s = v.x + v.y;
  float sq = v.x * v.x + v.y * v.y;
  for (int off = 32; off; off >>= 1) {
    s += __shfl_xor(s, off);
    sq += __shfl_xor(sq, off);
  }
  float m = s * (1.0f / 128.0f);
  float var = sq * (1.0f / 128.0f) - m * m;
  float r = rsqrtf(var + 1e-5f);
  float2 gg = ((const float2*)g)[lane];
  float2 bb = ((const float2*)b)[lane];
  float2 o;
  o.x = (v.x - m) * r * gg.x + bb.x;
  o.y = (v.y - m) * r * gg.y + bb.y;
  ((float2*)(out + (size_t)n * DIM))[lane] = o;
}

// ---------------- layernorm from buffer ----------------
__global__ __launch_bounds__(256) void ln_kernel(
    const float* __restrict__ in, const float* __restrict__ g,
    const float* __restrict__ b, float* __restrict__ out) {
  int wave = threadIdx.x >> 6;
  int lane = threadIdx.x & 63;
  int n = blockIdx.x * 4 + wave;
  if (n >= NN) return;
  float2 v = ((const float2*)(in + (size_t)n * DIM))[lane];
  float s = v.x + v.y;
  float sq = v.x * v.x + v.y * v.y;
  for (int off = 32; off; off >>= 1) {
    s += __shfl_xor(s, off);
    sq += __shfl_xor(sq, off);
  }
  float m = s * (1.0f / 128.0f);
  float var = sq * (1.0f / 128.0f) - m * m;
  float r = rsqrtf(var + 1e-5f);
  float2 gg = ((const float2*)g)[lane];
  float2 bb = ((const float2*)b)[lane];
  float2 o;
  o.x = (v.x - m) * r * gg.x + bb.x;
  o.y = (v.y - m) * r * gg.y + bb.y;
  ((float2*)(out + (size_t)n * DIM))[lane] = o;
}

// ---------------- CSR build ----------------
__global__ __launch_bounds__(256) void deg_int_kernel(const int* __restrict__ dst,
                                                      int* __restrict__ degi) {
  int e = blockIdx.x * 256 + threadIdx.x;
  if (e < NE) atomicAdd(degi + dst[e], 1);
}

__global__ __launch_bounds__(256) void scan1_kernel(const int* __restrict__ degi,
                                                    int* __restrict__ excl,
                                                    int* __restrict__ bsum) {
  __shared__ int tmp[256];
  int t = threadIdx.x;
  int i = blockIdx.x * 256 + t;
  int v = (i < NN) ? degi[i] : 0;
  int val = v;
  tmp[t] = val;
  __syncthreads();
  for (int off = 1; off < 256; off <<= 1) {
    int add = (t >= off) ? tmp[t - off] : 0;
    __syncthreads();
    val += add;
    tmp[t] = val;
    __syncthreads();
  }
  if (i < NN) excl[i] = val - v;
  if (t == 255) bsum[blockIdx.x] = val;
}

__global__ __launch_bounds__(512) void scan2_kernel(int* __restrict__ bsum,
                                                    int* __restrict__ bscan) {
  __shared__ int tmp[512];
  int t = threadIdx.x;
  int v = (t < NB_SCAN) ? bsum[t] : 0;
  int val = v;
  tmp[t] = val;
  __syncthreads();
  for (int off = 1; off < 512; off <<= 1) {
    int add = (t >= off) ? tmp[t - off] : 0;
    __syncthreads();
    val += add;
    tmp[t] = val;
    __syncthreads();
  }
  if (t < NB_SCAN) bscan[t] = val - v;
}

__global__ __launch_bounds__(256) void scan3_kernel(const int* __restrict__ excl,
                                                    const int* __restrict__ bscan,
                                                    int* __restrict__ row_off,
                                                    int* __restrict__ cursor) {
  int i = blockIdx.x * 256 + threadIdx.x;
  if (i < NN) {
    int r = excl[i] + bscan[i >> 8];
    row_off[i] = r;
    cursor[i] = r;
  }
  if (i == 0) row_off[NN] = NE;
}

__global__ __launch_bounds__(256) void fill_kernel(const int* __restrict__ src,
                                                   const int* __restrict__ dst,
                                                   int* __restrict__ cursor,
                                                   int* __restrict__ csr_src) {
  int e = blockIdx.x * 256 + threadIdx.x;
  if (e < NE) {
    int d = dst[e];
    int slot = atomicAdd(cursor + d, 1);
    csr_src[slot] = src[e];
  }
}

// ---------------- gather mean ----------------
__global__ __launch_bounds__(256) void gather_mean_kernel(
    const int* __restrict__ row_off, const int* __restrict__ csr_src,
    const float* __restrict__ x, float* __restrict__ agg) {
  int t = threadIdx.x;
  int q = t & 31;
  int node = blockIdx.x * 8 + (t >> 5);
  if (node >= NN) return;
  int beg = row_off[node], end = row_off[node + 1];
  float4 acc = make_float4(0.f, 0.f, 0.f, 0.f);
  for (int e = beg; e < end; ++e) {
    int s = csr_src[e];
    float4 v = ((const float4*)(x + (size_t)s * DIM))[q];
    acc.x += v.x; acc.y += v.y; acc.z += v.z; acc.w += v.w;
  }
  float sc = 1.0f / fmaxf((float)(end - beg), 1.0f);
  acc.x *= sc; acc.y *= sc; acc.z *= sc; acc.w *= sc;
  ((float4*)(agg + (size_t)node * DIM))[q] = acc;
}

// ---------------- weight split into per-lane fragment order ----------------
// wp layout: [p][hl][j][ht][lane][8] ushort; p=phase(0..3), hl=hi/lo, j=k32-block,
// ht=h-tile(0..7), lane=0..63. Lane (lq=lane>>4,l15=lane&15) elem e maps to
// h = ht*16+l15, k = p*64 + j*32 + lq*4 + (e&3) + 16*(e>>2). Coalesced 16B/lane.
__global__ __launch_bounds__(256) void prep_w_kernel(const float* __restrict__ wl,
                                                     const float* __restrict__ wr,
                                                     ushort* __restrict__ wp) {
  int t = blockIdx.x * 256 + threadIdx.x;  // 32768 = p*j*ht*lane*e
  int e = t & 7;
  int lane = (t >> 3) & 63;
  int ht = (t >> 9) & 7;
  int j = (t >> 12) & 1;
  int p = (t >> 13) & 3;
  int h = ht * 16 + (lane & 15);
  int lq = lane >> 4;
  int k = p * 64 + j * 32 + lq * 4 + (e & 3) + 16 * (e >> 2);
  float v = (k < 128) ? wl[h * 128 + k] : wr[h * 128 + (k - 128)];
  ushort hi = f2bf(v);
  ushort lo = f2bf(v - bf2f(hi));
  wp[(((p * 2 + 0) * 2 + j) * 8 + ht) * 512 + lane * 8 + e] = hi;
  wp[(((p * 2 + 1) * 2 + j) * 8 + ht) * 512 + lane * 8 + e] = lo;
}

// ---------------- SAGE conv via split-bf16 MFMA, W in LDS, T14 async prefetch ----
// out = relu([agg|x] @ Wcat^T + bl), K=256, 3-term split product.
// Block: 128 nodes x 128 h; 4 waves each 32 nodes x 128 h.
// Per phase: {ds_write regs staged last phase -> barrier -> ISSUE next-phase
// global loads -> MFMA cluster -> barrier}. Loads fly under the MFMAs.
__global__ __launch_bounds__(256, 2) void conv_mfma_kernel(
    const float* __restrict__ xln, const float* __restrict__ agg,
    const ushort* __restrict__ wp, const float* __restrict__ bl,
    float* __restrict__ out) {
  __shared__ ushort Xs[2][128 * 64];  // 32 KB: [hi/lo][row*64 + permuted k]
  __shared__ ushort Wl[16384];        // 32 KB: per-phase W slice [hl][j][ht][lane][8]
  const int t = threadIdx.x;
  const int lane = t & 63;
  const int wv = t >> 6;
  const int l15 = lane & 15;
  const int lq = lane >> 4;
  const int nbase = blockIdx.x * 128;

  f32x4 acc[2][8];
#pragma unroll
  for (int a = 0; a < 2; ++a)
#pragma unroll
    for (int b = 0; b < 8; ++b) acc[a][b] = (f32x4){0.f, 0.f, 0.f, 0.f};

  const int srow = t >> 1;   // staging row 0..127
  const int sh2 = t & 1;     // staging half
  const int gn_s = nbase + srow;
  const bool sval = gn_s < NN;
  char* lds_hi = (char*)&Xs[0][0];
  char* lds_lo = (char*)&Xs[1][0];
  const int sswz = (srow & 7) << 4;

  short8_t wreg[8];  // in-flight W slice portion (128B/thread)
  float4 xreg[8];    // in-flight X row-half (32 floats)

  // ---- load issue helpers (phase p) ----
#define LOADW(P)                                                              \
  {                                                                           \
    const ushort* wsrc = wp + (P) * 16384;                                    \
    _Pragma("unroll") for (int i = 0; i < 8; ++i)                             \
        wreg[i] = *(const short8_t*)(wsrc + i * 2048 + t * 8);                \
  }
#define LOADX(P)                                                              \
  {                                                                           \
    const float* srcp = ((P) < 2) ? agg : xln;                                \
    const int kb = ((P) & 1) * 64;                                            \
    _Pragma("unroll") for (int i = 0; i < 8; ++i) {                           \
      int qd = sh2 * 8 + i;                                                   \
      xreg[i] = make_float4(0.f, 0.f, 0.f, 0.f);                              \
      if (sval) xreg[i] = *(const float4*)(srcp + (size_t)gn_s * DIM + kb + qd * 4); \
    }                                                                         \
  }

  // prologue: issue phase-0 loads
  LOADW(0)
  LOADX(0)

  for (int p = 0; p < 4; ++p) {
    // ---- write staged regs to LDS (waits on the in-flight loads)
#pragma unroll
    for (int i = 0; i < 8; ++i)
      *(short8_t*)(Wl + i * 2048 + t * 8) = wreg[i];
#pragma unroll
    for (int i = 0; i < 8; ++i) {
      int qd = sh2 * 8 + i;  // float4-quad within phase (k = qd*4)
      float4 v = xreg[i];
      int j = qd >> 3;   // 32-k block
      int a = qd & 7;    // quad within block
      int inner = j * 64 + ((a < 4) ? a * 16 : (a - 4) * 16 + 8);
      int off = srow * 128 + inner;
      ushort4 hi, lo;
      hi.x = f2bf(v.x); lo.x = f2bf(v.x - bf2f(hi.x));
      hi.y = f2bf(v.y); lo.y = f2bf(v.y - bf2f(hi.y));
      hi.z = f2bf(v.z); lo.z = f2bf(v.z - bf2f(hi.z));
      hi.w = f2bf(v.w); lo.w = f2bf(v.w - bf2f(hi.w));
      *(ushort4*)(lds_hi + (off ^ sswz)) = hi;
      *(ushort4*)(lds_lo + (off ^ sswz)) = lo;
    }
    __syncthreads();
    // ---- issue next phase's global loads; they overlap the MFMAs below
    if (p < 3) {
      LOADW(p + 1)
      LOADX(p + 1)
    }
    // ---- compute: 2 k-steps of 32
#pragma unroll
    for (int j = 0; j < 2; ++j) {
      short8_t ahi[2], alo[2];
#pragma unroll
      for (int nt = 0; nt < 2; ++nt) {
        int row = wv * 32 + nt * 16 + l15;
        int off = row * 128 + j * 64 + lq * 16;
        int sw = (row & 7) << 4;
        ahi[nt] = *(short8_t*)(lds_hi + (off ^ sw));
        alo[nt] = *(short8_t*)(lds_lo + (off ^ sw));
      }
#pragma unroll
      for (int ht = 0; ht < 8; ++ht) {
        short8_t bhi = *(const short8_t*)(Wl + ((0 * 2 + j) * 8 + ht) * 512 + lane * 8);
        short8_t blo = *(const short8_t*)(Wl + ((1 * 2 + j) * 8 + ht) * 512 + lane * 8);
        acc[0][ht] = __builtin_amdgcn_mfma_f32_16x16x32_bf16(ahi[0], bhi, acc[0][ht], 0, 0, 0);
        acc[1][ht] = __builtin_amdgcn_mfma_f32_16x16x32_bf16(ahi[1], bhi, acc[1][ht], 0, 0, 0);
        acc[0][ht] = __builtin_amdgcn_mfma_f32_16x16x32_bf16(alo[0], bhi, acc[0][ht], 0, 0, 0);
        acc[1][ht] = __builtin_amdgcn_mfma_f32_16x16x32_bf16(alo[1], bhi, acc[1][ht], 0, 0, 0);
        acc[0][ht] = __builtin_amdgcn_mfma_f32_16x16x32_bf16(ahi[0], blo, acc[0][ht], 0, 0, 0);
        acc[1][ht] = __builtin_amdgcn_mfma_f32_16x16x32_bf16(ahi[1], blo, acc[1][ht], 0, 0, 0);
      }
    }
    __syncthreads();
  }
#undef LOADW
#undef LOADX
  // ---- epilogue: bias + relu, C layout col=lane&15, row=(lane>>4)*4+reg
#pragma unroll
  for (int ht = 0; ht < 8; ++ht) {
    float bv = bl[ht * 16 + l15];
#pragma unroll
    for (int nt = 0; nt < 2; ++nt) {
#pragma unroll
      for (int r = 0; r < 4; ++r) {
        int node = nbase + wv * 32 + nt * 16 + lq * 4 + r;
        if (node < NN)
          out[(size_t)node * DIM + ht * 16 + l15] = fmaxf(acc[nt][ht][r] + bv, 0.f);
      }
    }
  }
}

// ---------------- mean pool over sorted batch ----------------
#define PCHUNK 128
__global__ __launch_bounds__(128) void pool_kernel(const float* __restrict__ x,
                                                   const int* __restrict__ batch,
                                                   float* __restrict__ pool,
                                                   float* __restrict__ cnt) {
  int f = threadIdx.x;
  int n0 = blockIdx.x * PCHUNK;
  float acc = 0.f;
  int cur = batch[n0];
  int runlen = 0;
  for (int i = 0; i < PCHUNK; ++i) {
    int n = n0 + i;
    if (n >= NN) break;
    int bg = batch[n];
    if (bg != cur) {
      atomicAdd(&pool[cur * DIM + f], acc);
      if (f == 0) atomicAdd(&cnt[cur], (float)runlen);
      acc = 0.f;
      runlen = 0;
      cur = bg;
    }
    acc += x[(size_t)n * DIM + f];
    runlen++;
  }
  if (runlen > 0) {
    atomicAdd(&pool[cur * DIM + f], acc);
    if (f == 0) atomicAdd(&cnt[cur], (float)runlen);
  }
}

// ---------------- MLP head ----------------
__global__ __launch_bounds__(128) void head_kernel(
    const float* __restrict__ pool, const float* __restrict__ cnt,
    const float* __restrict__ w1, const float* __restrict__ b1,
    const float* __restrict__ w2, const float* __restrict__ b2,
    float* __restrict__ out) {
  __shared__ float gsh[128];
  __shared__ float h[64];
  int g = blockIdx.x;
  int t = threadIdx.x;
  float ic = 1.0f / fmaxf(cnt[g], 1.0f);
  gsh[t] = pool[g * DIM + t] * ic;
  __syncthreads();
  if (t < 64) {
    float a = b1[t];
#pragma unroll 8
    for (int k = 0; k < 128; ++k) a += gsh[k] * w1[t * 128 + k];
    h[t] = fmaxf(a, 0.f);
  }
  __syncthreads();
  if (t < 2) {
    float a = b2[t];
#pragma unroll
    for (int k = 0; k < 64; ++k) a += h[k] * w2[t * 64 + k];
    out[g * 2 + t] = a;
  }
}

extern "C" void kernel_launch(void* const* d_in, const int* in_sizes, int n_in,
                              void* d_out, int out_size, void* d_ws, size_t ws_size,
                              hipStream_t stream) {
  const int* x_idx = (const int*)d_in[0];
  const int* eidx = (const int*)d_in[1];
  const int* batch = (const int*)d_in[2];
  const float* emb = (const float*)d_in[3];
  const float* ln0g = (const float*)d_in[4];
  const float* ln0b = (const float*)d_in[5];
  const float* w0l = (const float*)d_in[6];
  const float* b0l = (const float*)d_in[7];
  const float* w0r = (const float*)d_in[8];
  const float* ln1g = (const float*)d_in[9];
  const float* ln1b = (const float*)d_in[10];
  const float* w1l = (const float*)d_in[11];
  const float* b1l = (const float*)d_in[12];
  const float* w1r = (const float*)d_in[13];
  const float* mw1 = (const float*)d_in[14];
  const float* mb1 = (const float*)d_in[15];
  const float* mw2 = (const float*)d_in[16];
  const float* mb2 = (const float*)d_in[17];
  float* out = (float*)d_out;

  float* ws = (float*)d_ws;
  float* x = ws;                                  // NN*DIM
  float* agg = x + (size_t)NN * DIM;              // NN*DIM
  float* pool = agg + (size_t)NN * DIM;           // NG*DIM
  float* cnt = pool + (size_t)NG * DIM;           // NG
  ushort* wp0 = (ushort*)(cnt + NG);              // 65536 ushort each
  ushort* wp1 = wp0 + 65536;
  int* degi = (int*)(wp1 + 65536);                // NN
  int* excl = degi + NN;                          // NN
  int* row_off = excl + NN;                       // NN+1
  int* cursor = row_off + NN + 1;                 // NN
  int* bsum = cursor + NN;                        // 512
  int* bscan = bsum + 512;                        // 512
  int* csr_src = bscan + 512;                     // NE

  const int* src = eidx;
  const int* dst = eidx + NE;

  hipMemsetAsync(pool, 0, ((size_t)NG * DIM + NG) * sizeof(float), stream);
  hipMemsetAsync(degi, 0, (size_t)NN * sizeof(int), stream);

  // CSR build (once, reused by both layers)
  deg_int_kernel<<<(NE + 255) / 256, 256, 0, stream>>>(dst, degi);
  scan1_kernel<<<NB_SCAN, 256, 0, stream>>>(degi, excl, bsum);
  scan2_kernel<<<1, 512, 0, stream>>>(bsum, bscan);
  scan3_kernel<<<NB_SCAN, 256, 0, stream>>>(excl, bscan, row_off, cursor);
  fill_kernel<<<(NE + 255) / 256, 256, 0, stream>>>(src, dst, cursor, csr_src);

  // weight split into per-lane fragment order
  prep_w_kernel<<<128, 256, 0, stream>>>(w0l, w0r, wp0);
  prep_w_kernel<<<128, 256, 0, stream>>>(w1l, w1r, wp1);

  embed_ln_kernel<<<NN / 4, 256, 0, stream>>>(x_idx, emb, ln0g, ln0b, x);

  // layer 0
  gather_mean_kernel<<<(NN + 7) / 8, 256, 0, stream>>>(row_off, csr_src, x, agg);
  conv_mfma_kernel<<<(NN + 127) / 128, 256, 0, stream>>>(x, agg, wp0, b0l, agg);
  // layer 1
  ln_kernel<<<NN / 4, 256, 0, stream>>>(agg, ln1g, ln1b, x);
  gather_mean_kernel<<<(NN + 7) / 8, 256, 0, stream>>>(row_off, csr_src, x, agg);
  conv_mfma_kernel<<<(NN + 127) / 128, 256, 0, stream>>>(x, agg, wp1, b1l, agg);

  pool_kernel<<<(NN + PCHUNK - 1) / PCHUNK, 128, 0, stream>>>(agg, batch, pool, cnt);
  head_kernel<<<NG, 128, 0, stream>>>(pool, cnt, mw1, mb1, mw2, mb2, out);
}

// Round 9
// 461.009 us; speedup vs baseline: 1.2727x; 1.0014x over previous
//
#include <hip/hip_runtime.h>

#define NN 100000
#define NE 600000
#define DIM 128
#define NG 256
#define NGRP 6250   // NN/16
#define NB_SCAN 391 // ceil(NN/256)

typedef __attribute__((ext_vector_type(8))) short short8_t;
typedef __attribute__((ext_vector_type(4))) float f32x4;

__device__ __forceinline__ ushort f2bf(float f) {
  unsigned u = __float_as_uint(f);
  unsigned r = (u + 0x7fffu + ((u >> 16) & 1u)) >> 16;
  return (ushort)r;
}
__device__ __forceinline__ float bf2f(ushort h) {
  return __uint_as_float(((unsigned)h) << 16);
}

// ---------------- embed + layernorm (wave per node) ----------------
__global__ __launch_bounds__(256) void embed_ln_kernel(
    const int* __restrict__ x_idx, const float* __restrict__ emb,
    const float* __restrict__ g, const float* __restrict__ b,
    float* __restrict__ out) {
  int wave = threadIdx.x >> 6;
  int lane = threadIdx.x & 63;
  int n = blockIdx.x * 4 + wave;
  if (n >= NN) return;
  int idx = x_idx[n];
  float2 v = ((const float2*)(emb + (size_t)idx * DIM))[lane];
  float s = v.x + v.y;
  float sq = v.x * v.x + v.y * v.y;
  for (int off = 32; off; off >>= 1) {
    s += __shfl_xor(s, off);
    sq += __shfl_xor(sq, off);
  }
  float m = s * (1.0f / 128.0f);
  float var = sq * (1.0f / 128.0f) - m * m;
  float r = rsqrtf(var + 1e-5f);
  float2 gg = ((const float2*)g)[lane];
  float2 bb = ((const float2*)b)[lane];
  float2 o;
  o.x = (v.x - m) * r * gg.x + bb.x;
  o.y = (v.y - m) * r * gg.y + bb.y;
  ((float2*)(out + (size_t)n * DIM))[lane] = o;
}

// ---------------- CSR build ----------------
__global__ __launch_bounds__(256) void deg_int_kernel(const int* __restrict__ dst,
                                                      int* __restrict__ degi) {
  int e = blockIdx.x * 256 + threadIdx.x;
  if (e < NE) atomicAdd(degi + dst[e], 1);
}

__global__ __launch_bounds__(256) void scan1_kernel(const int* __restrict__ degi,
                                                    int* __restrict__ excl,
                                                    int* __restrict__ bsum) {
  __shared__ int tmp[256];
  int t = threadIdx.x;
  int i = blockIdx.x * 256 + t;
  int v = (i < NN) ? degi[i] : 0;
  int val = v;
  tmp[t] = val;
  __syncthreads();
  for (int off = 1; off < 256; off <<= 1) {
    int add = (t >= off) ? tmp[t - off] : 0;
    __syncthreads();
    val += add;
    tmp[t] = val;
    __syncthreads();
  }
  if (i < NN) excl[i] = val - v;
  if (t == 255) bsum[blockIdx.x] = val;
}

__global__ __launch_bounds__(512) void scan2_kernel(int* __restrict__ bsum,
                                                    int* __restrict__ bscan) {
  __shared__ int tmp[512];
  int t = threadIdx.x;
  int v = (t < NB_SCAN) ? bsum[t] : 0;
  int val = v;
  tmp[t] = val;
  __syncthreads();
  for (int off = 1; off < 512; off <<= 1) {
    int add = (t >= off) ? tmp[t - off] : 0;
    __syncthreads();
    val += add;
    tmp[t] = val;
    __syncthreads();
  }
  if (t < NB_SCAN) bscan[t] = val - v;
}

__global__ __launch_bounds__(256) void scan3_kernel(const int* __restrict__ excl,
                                                    const int* __restrict__ bscan,
                                                    int* __restrict__ row_off,
                                                    int* __restrict__ cursor) {
  int i = blockIdx.x * 256 + threadIdx.x;
  if (i < NN) {
    int r = excl[i] + bscan[i >> 8];
    row_off[i] = r;
    cursor[i] = r;
  }
  if (i == 0) row_off[NN] = NE;
}

__global__ __launch_bounds__(256) void fill_kernel(const int* __restrict__ src,
                                                   const int* __restrict__ dst,
                                                   int* __restrict__ cursor,
                                                   int* __restrict__ csr_src) {
  int e = blockIdx.x * 256 + threadIdx.x;
  if (e < NE) {
    int d = dst[e];
    int slot = atomicAdd(cursor + d, 1);
    csr_src[slot] = src[e];
  }
}

// ---------------- gather mean -> fragment-layout agg ----------------
// af layout (ushort): [g16][jb(4)][lane(64)][hl(2)][e(8)], lane=(lq*16+l15),
// node n = g16*16+l15, k = jb*32 + lq*4 + (e&3) + 16*(e>>2).
__global__ __launch_bounds__(256) void gather_mean_kernel(
    const int* __restrict__ row_off, const int* __restrict__ csr_src,
    const float* __restrict__ x, ushort* __restrict__ af) {
  int t = threadIdx.x;
  int q = t & 31;
  int node = blockIdx.x * 8 + (t >> 5);
  if (node >= NN) return;
  int beg = row_off[node], end = row_off[node + 1];
  float4 acc = make_float4(0.f, 0.f, 0.f, 0.f);
  for (int e = beg; e < end; ++e) {
    int s = csr_src[e];
    float4 v = ((const float4*)(x + (size_t)s * DIM))[q];
    acc.x += v.x; acc.y += v.y; acc.z += v.z; acc.w += v.w;
  }
  float sc = 1.0f / fmaxf((float)(end - beg), 1.0f);
  acc.x *= sc; acc.y *= sc; acc.z *= sc; acc.w *= sc;
  // split + fragment write
  ushort4 hi, lo;
  hi.x = f2bf(acc.x); lo.x = f2bf(acc.x - bf2f(hi.x));
  hi.y = f2bf(acc.y); lo.y = f2bf(acc.y - bf2f(hi.y));
  hi.z = f2bf(acc.z); lo.z = f2bf(acc.z - bf2f(hi.z));
  hi.w = f2bf(acc.w); lo.w = f2bf(acc.w - bf2f(hi.w));
  int g = node >> 4, l15n = node & 15;
  int jb = q >> 3, lqw = q & 3, ebase = q & 4;
  size_t base = (((size_t)g * 4 + jb) * 64 + lqw * 16 + l15n) * 16;
  *(ushort4*)(af + base + ebase) = hi;
  *(ushort4*)(af + base + 8 + ebase) = lo;
}

// ---------------- weight split into per-lane fragment order ----------------
// wp layout: [p][hl][j][ht][lane][8]; k = p*64 + j*32 + lq*4 + (e&3) + 16*(e>>2);
// k<128 -> wl (agg term, phases p=0,1), k>=128 -> wr (self term, p=2,3).
__global__ __launch_bounds__(256) void prep_w_kernel(const float* __restrict__ wl,
                                                     const float* __restrict__ wr,
                                                     ushort* __restrict__ wp) {
  int t = blockIdx.x * 256 + threadIdx.x;  // 32768
  int e = t & 7;
  int lane = (t >> 3) & 63;
  int ht = (t >> 9) & 7;
  int j = (t >> 12) & 1;
  int p = (t >> 13) & 3;
  int h = ht * 16 + (lane & 15);
  int lq = lane >> 4;
  int k = p * 64 + j * 32 + lq * 4 + (e & 3) + 16 * (e >> 2);
  float v = (k < 128) ? wl[h * 128 + k] : wr[h * 128 + (k - 128)];
  ushort hi = f2bf(v);
  ushort lo = f2bf(v - bf2f(hi));
  wp[(((p * 2 + 0) * 2 + j) * 8 + ht) * 512 + lane * 8 + e] = hi;
  wp[(((p * 2 + 1) * 2 + j) * 8 + ht) * 512 + lane * 8 + e] = lo;
}

// ---------------- SAGE conv v3 ----------------
// out = relu([agg|x] @ Wcat^T + bl)  (+ optional fused LayerNorm), fp32 out.
// Phases 0,1: x self-half staged in LDS (32 KB, 3 barriers total).
// Phases 2,3: agg half read directly from fragment-layout af (no LDS).
// B fragments read directly from wp (coalesced, L2-resident).
__global__ __launch_bounds__(256, 3) void conv_mfma_kernel(
    const float* __restrict__ xln, const ushort* __restrict__ af,
    const ushort* __restrict__ wp, const float* __restrict__ bl,
    const float* __restrict__ lng, const float* __restrict__ lnb,
    float* __restrict__ out, int do_ln) {
  __shared__ ushort Xs[2][128 * 64];  // 32 KB: [hi/lo][row*64 + permuted k]
  const int t = threadIdx.x;
  const int lane = t & 63;
  const int wv = t >> 6;
  const int l15 = lane & 15;
  const int lq = lane >> 4;
  const int nbase = blockIdx.x * 128;

  f32x4 acc[2][8];
#pragma unroll
  for (int a = 0; a < 2; ++a)
#pragma unroll
    for (int b = 0; b < 8; ++b) acc[a][b] = (f32x4){0.f, 0.f, 0.f, 0.f};

  const int srow = t >> 1;
  const int sh2 = t & 1;
  const int gn_s = nbase + srow;
  const bool sval = gn_s < NN;
  char* lds_hi = (char*)&Xs[0][0];
  char* lds_lo = (char*)&Xs[1][0];
  const int sswz = (srow & 7) << 4;

  // ======== phases 0,1: x self-half (staged), W slice pk = ph+2 ========
#pragma unroll 1
  for (int ph = 0; ph < 2; ++ph) {
    if (ph) __syncthreads();
    const int kb = ph * 64;
#pragma unroll
    for (int i = 0; i < 8; ++i) {
      int qd = sh2 * 8 + i;
      float4 v = make_float4(0.f, 0.f, 0.f, 0.f);
      if (sval) v = *(const float4*)(xln + (size_t)gn_s * DIM + kb + qd * 4);
      int j = qd >> 3;
      int a = qd & 7;
      int inner = j * 64 + ((a < 4) ? a * 16 : (a - 4) * 16 + 8);
      int off = srow * 128 + inner;
      ushort4 hi, lo;
      hi.x = f2bf(v.x); lo.x = f2bf(v.x - bf2f(hi.x));
      hi.y = f2bf(v.y); lo.y = f2bf(v.y - bf2f(hi.y));
      hi.z = f2bf(v.z); lo.z = f2bf(v.z - bf2f(hi.z));
      hi.w = f2bf(v.w); lo.w = f2bf(v.w - bf2f(hi.w));
      *(ushort4*)(lds_hi + (off ^ sswz)) = hi;
      *(ushort4*)(lds_lo + (off ^ sswz)) = lo;
    }
    __syncthreads();
    const int pk = ph + 2;  // wr half of Wcat
#pragma unroll
    for (int j = 0; j < 2; ++j) {
      short8_t ahi[2], alo[2];
#pragma unroll
      for (int nt = 0; nt < 2; ++nt) {
        int row = wv * 32 + nt * 16 + l15;
        int off = row * 128 + j * 64 + lq * 16;
        int sw = (row & 7) << 4;
        ahi[nt] = *(short8_t*)(lds_hi + (off ^ sw));
        alo[nt] = *(short8_t*)(lds_lo + (off ^ sw));
      }
#pragma unroll
      for (int ht = 0; ht < 8; ++ht) {
        short8_t bhi = *(const short8_t*)(wp + (((pk * 2 + 0) * 2 + j) * 8 + ht) * 512 + lane * 8);
        short8_t blo = *(const short8_t*)(wp + (((pk * 2 + 1) * 2 + j) * 8 + ht) * 512 + lane * 8);
        acc[0][ht] = __builtin_amdgcn_mfma_f32_16x16x32_bf16(ahi[0], bhi, acc[0][ht], 0, 0, 0);
        acc[1][ht] = __builtin_amdgcn_mfma_f32_16x16x32_bf16(ahi[1], bhi, acc[1][ht], 0, 0, 0);
        acc[0][ht] = __builtin_amdgcn_mfma_f32_16x16x32_bf16(alo[0], bhi, acc[0][ht], 0, 0, 0);
        acc[1][ht] = __builtin_amdgcn_mfma_f32_16x16x32_bf16(alo[1], bhi, acc[1][ht], 0, 0, 0);
        acc[0][ht] = __builtin_amdgcn_mfma_f32_16x16x32_bf16(ahi[0], blo, acc[0][ht], 0, 0, 0);
        acc[1][ht] = __builtin_amdgcn_mfma_f32_16x16x32_bf16(ahi[1], blo, acc[1][ht], 0, 0, 0);
      }
    }
  }

  // ======== phases 2,3: agg half direct from fragments, W slice pk = ph-2 ====
  const int gblk = blockIdx.x * 8 + wv * 2;
#pragma unroll 1
  for (int ph = 2; ph < 4; ++ph) {
    const int pk = ph - 2;  // wl half of Wcat
#pragma unroll
    for (int j = 0; j < 2; ++j) {
      int jb = (ph & 1) * 2 + j;
      short8_t ahi[2], alo[2];
#pragma unroll
      for (int nt = 0; nt < 2; ++nt) {
        int g = gblk + nt;
        if (g < NGRP) {
          size_t base = (((size_t)g * 4 + jb) * 64 + lane) * 16;
          ahi[nt] = *(const short8_t*)(af + base);
          alo[nt] = *(const short8_t*)(af + base + 8);
        } else {
          ahi[nt] = (short8_t){0, 0, 0, 0, 0, 0, 0, 0};
          alo[nt] = (short8_t){0, 0, 0, 0, 0, 0, 0, 0};
        }
      }
#pragma unroll
      for (int ht = 0; ht < 8; ++ht) {
        short8_t bhi = *(const short8_t*)(wp + (((pk * 2 + 0) * 2 + j) * 8 + ht) * 512 + lane * 8);
        short8_t blo = *(const short8_t*)(wp + (((pk * 2 + 1) * 2 + j) * 8 + ht) * 512 + lane * 8);
        acc[0][ht] = __builtin_amdgcn_mfma_f32_16x16x32_bf16(ahi[0], bhi, acc[0][ht], 0, 0, 0);
        acc[1][ht] = __builtin_amdgcn_mfma_f32_16x16x32_bf16(ahi[1], bhi, acc[1][ht], 0, 0, 0);
        acc[0][ht] = __builtin_amdgcn_mfma_f32_16x16x32_bf16(alo[0], bhi, acc[0][ht], 0, 0, 0);
        acc[1][ht] = __builtin_amdgcn_mfma_f32_16x16x32_bf16(alo[1], bhi, acc[1][ht], 0, 0, 0);
        acc[0][ht] = __builtin_amdgcn_mfma_f32_16x16x32_bf16(ahi[0], blo, acc[0][ht], 0, 0, 0);
        acc[1][ht] = __builtin_amdgcn_mfma_f32_16x16x32_bf16(ahi[1], blo, acc[1][ht], 0, 0, 0);
      }
    }
  }

  // ======== epilogue: bias + relu (+ fused LN), fp32 row-major store ========
#pragma unroll
  for (int ht = 0; ht < 8; ++ht) {
    float bv = bl[ht * 16 + l15];
#pragma unroll
    for (int nt = 0; nt < 2; ++nt)
#pragma unroll
      for (int r = 0; r < 4; ++r) acc[nt][ht][r] = fmaxf(acc[nt][ht][r] + bv, 0.f);
  }
  if (do_ln) {
    float gg[8], bb[8];
#pragma unroll
    for (int ht = 0; ht < 8; ++ht) {
      gg[ht] = lng[ht * 16 + l15];
      bb[ht] = lnb[ht * 16 + l15];
    }
#pragma unroll
    for (int nt = 0; nt < 2; ++nt) {
#pragma unroll
      for (int r = 0; r < 4; ++r) {
        float s = 0.f, sq = 0.f;
#pragma unroll
        for (int ht = 0; ht < 8; ++ht) {
          float v = acc[nt][ht][r];
          s += v;
          sq += v * v;
        }
#pragma unroll
        for (int msk = 1; msk < 16; msk <<= 1) {
          s += __shfl_xor(s, msk);
          sq += __shfl_xor(sq, msk);
        }
        float m = s * (1.0f / 128.0f);
        float var = sq * (1.0f / 128.0f) - m * m;
        float rstd = rsqrtf(var + 1e-5f);
        int node = nbase + wv * 32 + nt * 16 + lq * 4 + r;
        if (node < NN) {
#pragma unroll
          for (int ht = 0; ht < 8; ++ht)
            out[(size_t)node * DIM + ht * 16 + l15] =
                (acc[nt][ht][r] - m) * rstd * gg[ht] + bb[ht];
        }
      }
    }
  } else {
#pragma unroll
    for (int nt = 0; nt < 2; ++nt) {
#pragma unroll
      for (int r = 0; r < 4; ++r) {
        int node = nbase + wv * 32 + nt * 16 + lq * 4 + r;
        if (node < NN) {
#pragma unroll
          for (int ht = 0; ht < 8; ++ht)
            out[(size_t)node * DIM + ht * 16 + l15] = acc[nt][ht][r];
        }
      }
    }
  }
}

// ---------------- mean pool over sorted batch ----------------
#define PCHUNK 128
__global__ __launch_bounds__(128) void pool_kernel(const float* __restrict__ x,
                                                   const int* __restrict__ batch,
                                                   float* __restrict__ pool,
                                                   float* __restrict__ cnt) {
  int f = threadIdx.x;
  int n0 = blockIdx.x * PCHUNK;
  float acc = 0.f;
  int cur = batch[n0];
  int runlen = 0;
  for (int i = 0; i < PCHUNK; ++i) {
    int n = n0 + i;
    if (n >= NN) break;
    int bg = batch[n];
    if (bg != cur) {
      atomicAdd(&pool[cur * DIM + f], acc);
      if (f == 0) atomicAdd(&cnt[cur], (float)runlen);
      acc = 0.f;
      runlen = 0;
      cur = bg;
    }
    acc += x[(size_t)n * DIM + f];
    runlen++;
  }
  if (runlen > 0) {
    atomicAdd(&pool[cur * DIM + f], acc);
    if (f == 0) atomicAdd(&cnt[cur], (float)runlen);
  }
}

// ---------------- MLP head ----------------
__global__ __launch_bounds__(128) void head_kernel(
    const float* __restrict__ pool, const float* __restrict__ cnt,
    const float* __restrict__ w1, const float* __restrict__ b1,
    const float* __restrict__ w2, const float* __restrict__ b2,
    float* __restrict__ out) {
  __shared__ float gsh[128];
  __shared__ float h[64];
  int g = blockIdx.x;
  int t = threadIdx.x;
  float ic = 1.0f / fmaxf(cnt[g], 1.0f);
  gsh[t] = pool[g * DIM + t] * ic;
  __syncthreads();
  if (t < 64) {
    float a = b1[t];
#pragma unroll 8
    for (int k = 0; k < 128; ++k) a += gsh[k] * w1[t * 128 + k];
    h[t] = fmaxf(a, 0.f);
  }
  __syncthreads();
  if (t < 2) {
    float a = b2[t];
#pragma unroll
    for (int k = 0; k < 64; ++k) a += h[k] * w2[t * 64 + k];
    out[g * 2 + t] = a;
  }
}

extern "C" void kernel_launch(void* const* d_in, const int* in_sizes, int n_in,
                              void* d_out, int out_size, void* d_ws, size_t ws_size,
                              hipStream_t stream) {
  const int* x_idx = (const int*)d_in[0];
  const int* eidx = (const int*)d_in[1];
  const int* batch = (const int*)d_in[2];
  const float* emb = (const float*)d_in[3];
  const float* ln0g = (const float*)d_in[4];
  const float* ln0b = (const float*)d_in[5];
  const float* w0l = (const float*)d_in[6];
  const float* b0l = (const float*)d_in[7];
  const float* w0r = (const float*)d_in[8];
  const float* ln1g = (const float*)d_in[9];
  const float* ln1b = (const float*)d_in[10];
  const float* w1l = (const float*)d_in[11];
  const float* b1l = (const float*)d_in[12];
  const float* w1r = (const float*)d_in[13];
  const float* mw1 = (const float*)d_in[14];
  const float* mb1 = (const float*)d_in[15];
  const float* mw2 = (const float*)d_in[16];
  const float* mb2 = (const float*)d_in[17];
  float* out = (float*)d_out;

  float* ws = (float*)d_ws;
  float* x = ws;                                  // NN*DIM fp32
  ushort* af = (ushort*)(x + (size_t)NN * DIM);   // NN*DIM*2 ushort (frag agg)
  float* pool = (float*)(af + (size_t)NN * DIM * 2);  // NG*DIM
  float* cnt = pool + (size_t)NG * DIM;           // NG
  ushort* wp0 = (ushort*)(cnt + NG);              // 65536 ushort each
  ushort* wp1 = wp0 + 65536;
  int* degi = (int*)(wp1 + 65536);                // NN
  int* excl = degi + NN;                          // NN
  int* row_off = excl + NN;                       // NN+1
  int* cursor = row_off + NN + 1;                 // NN
  int* bsum = cursor + NN;                        // 512
  int* bscan = bsum + 512;                        // 512
  int* csr_src = bscan + 512;                     // NE

  const int* src = eidx;
  const int* dst = eidx + NE;

  hipMemsetAsync(pool, 0, ((size_t)NG * DIM + NG) * sizeof(float), stream);
  hipMemsetAsync(degi, 0, (size_t)NN * sizeof(int), stream);

  // CSR build (once, reused by both layers)
  deg_int_kernel<<<(NE + 255) / 256, 256, 0, stream>>>(dst, degi);
  scan1_kernel<<<NB_SCAN, 256, 0, stream>>>(degi, excl, bsum);
  scan2_kernel<<<1, 512, 0, stream>>>(bsum, bscan);
  scan3_kernel<<<NB_SCAN, 256, 0, stream>>>(excl, bscan, row_off, cursor);
  fill_kernel<<<(NE + 255) / 256, 256, 0, stream>>>(src, dst, cursor, csr_src);

  // weight split into per-lane fragment order
  prep_w_kernel<<<128, 256, 0, stream>>>(w0l, w0r, wp0);
  prep_w_kernel<<<128, 256, 0, stream>>>(w1l, w1r, wp1);

  embed_ln_kernel<<<NN / 4, 256, 0, stream>>>(x_idx, emb, ln0g, ln0b, x);

  // layer 0 (conv epilogue applies LN1, writes x in place)
  gather_mean_kernel<<<(NN + 7) / 8, 256, 0, stream>>>(row_off, csr_src, x, af);
  conv_mfma_kernel<<<(NN + 127) / 128, 256, 0, stream>>>(x, af, wp0, b0l, ln1g, ln1b, x, 1);
  // layer 1 (plain relu epilogue, writes x in place)
  gather_mean_kernel<<<(NN + 7) / 8, 256, 0, stream>>>(row_off, csr_src, x, af);
  conv_mfma_kernel<<<(NN + 127) / 128, 256, 0, stream>>>(x, af, wp1, b1l, (const float*)0, (const float*)0, x, 0);

  pool_kernel<<<(NN + PCHUNK - 1) / PCHUNK, 128, 0, stream>>>(x, batch, pool, cnt);
  head_kernel<<<NG, 128, 0, stream>>>(pool, cnt, mw1, mb1, mw2, mb2, out);
}